// Round 7
// baseline (198.875 us; speedup 1.0000x reference)
//
#include <hip/hip_runtime.h>
#include <math.h>

// MultiHeadAttention: B=2, S=2048, D=1024, H=16, Dh=64, fp32 in/out.
// Round 7:
//  - attn: QBLK=128/block (4 waves x 32 q-rows, 2 groups/wave). Shared K/V
//    frag reads feed both groups (2 MFMA per LDS read); dbuf K/V; one raw
//    s_barrier + vmcnt(0) drain per iter AFTER compute; paired-qt grid for
//    uniform per-CU work (heavy+light block per CU).
//  - GEMM: QKV epilogue reverted to R4 direct stores (R5 staged epilogue
//    regressed ~10us); QSCALE folded into Q store.

#define H_  16
#define DH_ 64
#define D_  1024
#define S_  2048
#define B_  2

typedef __attribute__((ext_vector_type(8))) short short8;
typedef __attribute__((ext_vector_type(4))) float f32x4;

#define QSCALE 0.18033688011112042f      // log2(e)/8, folded into Q
#define DEFER_THR 11.5416f               // 8*log2(e): defer-max threshold

__device__ __forceinline__ unsigned short f2bf(float f) {
    union { float f; unsigned int u; } v; v.f = f;
    unsigned int r = (v.u + 0x7fffu + ((v.u >> 16) & 1u)) >> 16;   // RNE
    return (unsigned short)r;
}

__device__ __forceinline__ unsigned cvt_pk_bf16(float lo, float hi) {
    unsigned r;
    asm("v_cvt_pk_bf16_f32 %0, %1, %2" : "=v"(r) : "v"(lo), "v"(hi));
    return r;
}

__device__ __forceinline__ float fast_exp2(float x) {
#if __has_builtin(__builtin_amdgcn_exp2f)
    return __builtin_amdgcn_exp2f(x);
#else
    return exp2f(x);
#endif
}

__device__ __forceinline__ void gload_lds16(const void* g, void* l) {
    __builtin_amdgcn_global_load_lds(
        (const __attribute__((address_space(1))) void*)g,
        (__attribute__((address_space(3))) void*)l, 16, 0, 0);
}

// vmcnt(0) drain + workgroup barrier, WITHOUT lgkm drain (P-tile is per-wave).
#define SYNC_VM0() asm volatile("s_waitcnt vmcnt(0)\n\ts_barrier" ::: "memory")

// ---------------------------------------------------------------------------
// x fp32 [4096][1024] -> bf16. 8 elems/thread.
// ---------------------------------------------------------------------------
__global__ __launch_bounds__(256) void cvt_x_k(const float* __restrict__ x,
                                               unsigned short* __restrict__ xb)
{
    int i = (blockIdx.x * 256 + threadIdx.x) * 8;
    float4 a = *(const float4*)&x[i];
    float4 b = *(const float4*)&x[i + 4];
    uint4 o;
    o.x = f2bf(a.x) | ((unsigned)f2bf(a.y) << 16);
    o.y = f2bf(a.z) | ((unsigned)f2bf(a.w) << 16);
    o.z = f2bf(b.x) | ((unsigned)f2bf(b.y) << 16);
    o.w = f2bf(b.z) | ((unsigned)f2bf(b.w) << 16);
    *(uint4*)&xb[i] = o;
}

// ---------------------------------------------------------------------------
// W fp32 [k][n] -> Wt bf16 [n][k]. 64x64 LDS-tiled transpose. z: Wq/Wk/Wv/Wo.
// ---------------------------------------------------------------------------
__global__ __launch_bounds__(256) void tr_w_k(
    const float* __restrict__ W0, const float* __restrict__ W1,
    const float* __restrict__ W2, const float* __restrict__ W3,
    unsigned short* __restrict__ wt)
{
    const float* W = W0;
    if (blockIdx.z == 1) W = W1; else if (blockIdx.z == 2) W = W2;
    else if (blockIdx.z == 3) W = W3;
    unsigned short* out = wt + (size_t)blockIdx.z * 1048576;

    __shared__ float t[64][65];
    const int k0 = blockIdx.x * 64, n0 = blockIdx.y * 64;
    const int r = threadIdx.x >> 4, c4 = (threadIdx.x & 15) * 4;

    #pragma unroll
    for (int p = 0; p < 4; ++p) {
        float4 v = *(const float4*)&W[(size_t)(k0 + r + 16 * p) * D_ + n0 + c4];
        t[r + 16 * p][c4 + 0] = v.x; t[r + 16 * p][c4 + 1] = v.y;
        t[r + 16 * p][c4 + 2] = v.z; t[r + 16 * p][c4 + 3] = v.w;
    }
    __syncthreads();
    #pragma unroll
    for (int p = 0; p < 4; ++p) {
        int nn = r + 16 * p;
        uint2 o;
        o.x = f2bf(t[c4 + 0][nn]) | ((unsigned)f2bf(t[c4 + 1][nn]) << 16);
        o.y = f2bf(t[c4 + 2][nn]) | ((unsigned)f2bf(t[c4 + 3][nn]) << 16);
        *(uint2*)&out[(size_t)(n0 + nn) * D_ + k0 + c4] = o;
    }
}

// ---------------------------------------------------------------------------
// bf16 MFMA GEMM, 128x128 tile, BK=64, 4 waves (2x2), 4x4 frags.
// LDS XOR-slot swizzle, global_load_lds staging. Direct-store epilogue (R4).
// QKV=1: z selects q/k/v; Q (pre-scaled by QSCALE), K -> bf16 [B,H,S,64];
//        V -> bf16 [B,H,64,S].
// QKV=0: fp32 row-major + bias.
// ---------------------------------------------------------------------------
template<int QKV>
__global__ __launch_bounds__(256) void gemm_bf16(
    const unsigned short* __restrict__ Ab,
    const unsigned short* __restrict__ Wt,
    const float* __restrict__ b0, const float* __restrict__ b1,
    const float* __restrict__ b2,
    void* __restrict__ o0, void* __restrict__ o1, void* __restrict__ o2)
{
    const unsigned short* W = Wt;
    const float* bias = b0;
    int z = 0;
    if (QKV) {
        z = blockIdx.z;
        W = Wt + (size_t)z * 1048576;
        if (z == 1) bias = b1; else if (z == 2) bias = b2;
    }
    const int n0 = blockIdx.x * 128, j0 = blockIdx.y * 128;
    const int tid = threadIdx.x;
    const int lane = tid & 63;
    const int wq = tid >> 6, wm = wq >> 1, wn = wq & 1;
    const int lr = lane & 15, lk = lane >> 4;

    __shared__ __align__(16) char smem[32768];

    f32x4 acc[4][4] = {};

    for (int k0 = 0; k0 < D_; k0 += 64) {
        __syncthreads();
        #pragma unroll
        for (int c = 0; c < 4; ++c) {
            int u = c * 256 + tid;
            int r = u >> 3, sp = u & 7, sl = sp ^ (r & 7);
            gload_lds16(&Ab[(size_t)(n0 + r) * D_ + k0 + sl * 8], &smem[u * 16]);
        }
        #pragma unroll
        for (int c = 0; c < 4; ++c) {
            int u = c * 256 + tid;
            int r = u >> 3, sp = u & 7, sl = sp ^ (r & 7);
            gload_lds16(&W[(size_t)(j0 + r) * D_ + k0 + sl * 8],
                        &smem[16384 + u * 16]);
        }
        __syncthreads();
        #pragma unroll
        for (int kc = 0; kc < 2; ++kc) {
            short8 a[4], b[4];
            #pragma unroll
            for (int m = 0; m < 4; ++m) {
                int row = wm * 64 + m * 16 + lr;
                int sp = (kc * 4 + lk) ^ (row & 7);
                a[m] = *(const short8*)&smem[row * 128 + sp * 16];
            }
            #pragma unroll
            for (int n = 0; n < 4; ++n) {
                int row = wn * 64 + n * 16 + lr;
                int sp = (kc * 4 + lk) ^ (row & 7);
                b[n] = *(const short8*)&smem[16384 + row * 128 + sp * 16];
            }
            #pragma unroll
            for (int m = 0; m < 4; ++m)
                #pragma unroll
                for (int n = 0; n < 4; ++n)
                    acc[m][n] = __builtin_amdgcn_mfma_f32_16x16x32_bf16(
                        a[m], b[n], acc[m][n], 0, 0, 0);
        }
    }

    float bn[4];
    #pragma unroll
    for (int n = 0; n < 4; ++n) bn[n] = bias[j0 + wn * 64 + n * 16 + lr];

    #pragma unroll
    for (int m = 0; m < 4; ++m) {
        #pragma unroll
        for (int n = 0; n < 4; ++n) {
            int col = j0 + wn * 64 + n * 16 + lr;
            int row0 = n0 + wm * 64 + m * 16 + lk * 4;
            if (QKV) {
                int head = col >> 6, dh = col & 63;
                int bb = row0 >> 11, s0 = row0 & (S_ - 1);
                float v0 = acc[m][n][0] + bn[n], v1 = acc[m][n][1] + bn[n];
                float v2 = acc[m][n][2] + bn[n], v3 = acc[m][n][3] + bn[n];
                if (z < 2) {            // Q (scaled), K -> [B,H,S,64]
                    const float sc = (z == 0) ? QSCALE : 1.0f;
                    unsigned short* out = (unsigned short*)(z == 0 ? o0 : o1);
                    size_t base = ((size_t)((bb << 4) + head) * S_) * 64 + dh;
                    out[base + (size_t)(s0 + 0) * 64] = f2bf(v0 * sc);
                    out[base + (size_t)(s0 + 1) * 64] = f2bf(v1 * sc);
                    out[base + (size_t)(s0 + 2) * 64] = f2bf(v2 * sc);
                    out[base + (size_t)(s0 + 3) * 64] = f2bf(v3 * sc);
                } else {                // V -> [B,H,64,S]
                    unsigned short* out = (unsigned short*)o2;
                    uint2 pk;
                    pk.x = f2bf(v0) | ((unsigned)f2bf(v1) << 16);
                    pk.y = f2bf(v2) | ((unsigned)f2bf(v3) << 16);
                    *(uint2*)&out[((size_t)((bb << 4) + head) * 64 + dh) * S_ + s0] = pk;
                }
            } else {
                float* out = (float*)o0;
                #pragma unroll
                for (int r = 0; r < 4; ++r)
                    out[(size_t)(row0 + r) * D_ + col] = acc[m][n][r] + bn[n];
            }
        }
    }
}

// ---------------------------------------------------------------------------
// MFMA flash attention, QBLK=128, double-buffered. grid = (B*H, 16), 4 waves.
// Wave owns 32 q-rows (2 groups of 16); K/V frag reads shared across groups.
// qt pairing: y<8 -> 15-y (heavy), else y-8 (light) -> uniform per-CU work.
// LDS: buf0 [0,16K), buf1 [16K,32K), P tiles [32K,48K) (2KB per wave-group).
// ---------------------------------------------------------------------------
__global__ __launch_bounds__(256) void attn_mfma(
    const unsigned short* __restrict__ q, const unsigned short* __restrict__ k,
    const unsigned short* __restrict__ vt, unsigned short* __restrict__ ctx)
{
    const int bh = blockIdx.x;          // b*H + h
    const int yt = blockIdx.y;          // 0..15
    const int qt = (yt < 8) ? (15 - yt) : (yt - 8);
    const int nkt = 2 * qt + 2;         // kv tiles of 64
    const int tid = threadIdx.x;
    const int lane = tid & 63, wq = tid >> 6;
    const int lx = lane & 15, hi = lane >> 4;

    __shared__ __align__(16) char smem[49152];
    char* Pw0 = &smem[32768 + wq * 4096];
    char* Pw1 = Pw0 + 2048;

    const int b = bh >> 4, h = bh & (H_ - 1);

    // Q fragments: group g rows = qt*128 + wq*32 + g*16 + lx
    short8 qf[2][2];
    #pragma unroll
    for (int g = 0; g < 2; ++g) {
        const unsigned short* qrow =
            q + ((size_t)bh * S_ + qt * 128 + wq * 32 + g * 16 + lx) * 64;
        qf[g][0] = *(const short8*)&qrow[hi * 8];
        qf[g][1] = *(const short8*)&qrow[32 + hi * 8];
    }

    f32x4 o0[4] = {}, o1[4] = {};       // O[g][hi*4+r][ct*16+lx]
    float m0 = -INFINITY, m1 = -INFINITY, l0 = 0.f, l1 = 0.f;
    const int qg0 = qt * 128 + wq * 32 + lx;
    const int qg1 = qg0 + 16;

    // ---- prologue: stage tile 0 into buf0 ----
    #pragma unroll
    for (int c = 0; c < 2; ++c) {
        int u = c * 256 + tid;
        int r = u >> 3, sp = u & 7, sl = sp ^ (r & 7);
        gload_lds16(&k[((size_t)bh * S_ + r) * 64 + sl * 8], &smem[u * 16]);
    }
    #pragma unroll
    for (int c = 0; c < 2; ++c) {
        int u = c * 256 + tid;
        int r = u >> 3, sp = u & 7, sl = sp ^ (r & 7);
        gload_lds16(&vt[((size_t)bh * 64 + r) * S_ + sl * 8],
                    &smem[8192 + u * 16]);
    }
    SYNC_VM0();

    int cur = 0;
    for (int kt = 0; kt < nkt; ++kt) {
        char* bufc = smem + cur * 16384;

        // ---- stage t+1 (latency hides under compute) ----
        if (kt + 1 < nkt) {
            char* bufn = smem + (cur ^ 1) * 16384;
            #pragma unroll
            for (int c = 0; c < 2; ++c) {
                int u = c * 256 + tid;
                int r = u >> 3, sp = u & 7, sl = sp ^ (r & 7);
                gload_lds16(&k[((size_t)bh * S_ + (kt + 1) * 64 + r) * 64 + sl * 8],
                            &bufn[u * 16]);
            }
            #pragma unroll
            for (int c = 0; c < 2; ++c) {
                int u = c * 256 + tid;
                int r = u >> 3, sp = u & 7, sl = sp ^ (r & 7);
                gload_lds16(&vt[((size_t)bh * 64 + r) * S_ + (kt + 1) * 64 + sl * 8],
                            &bufn[8192 + u * 16]);
            }
        }

        // ---- QK^T (swapped): each kf feeds both q-groups ----
        f32x4 s0[4] = {}, s1[4] = {};
        #pragma unroll
        for (int rt = 0; rt < 4; ++rt) {
            #pragma unroll
            for (int ks = 0; ks < 2; ++ks) {
                int row = rt * 16 + lx;
                int sp = (ks * 4 + hi) ^ (row & 7);
                short8 kf = *(const short8*)&bufc[row * 128 + sp * 16];
                s0[rt] = __builtin_amdgcn_mfma_f32_16x16x32_bf16(
                    kf, qf[0][ks], s0[rt], 0, 0, 0);
                s1[rt] = __builtin_amdgcn_mfma_f32_16x16x32_bf16(
                    kf, qf[1][ks], s1[rt], 0, 0, 0);
            }
        }

        // ---- causal mask (only tiles overlapping this block's diagonal) ----
        if (kt >= 2 * qt) {
            #pragma unroll
            for (int rt = 0; rt < 4; ++rt)
                #pragma unroll
                for (int r = 0; r < 4; ++r) {
                    int kvg = kt * 64 + rt * 16 + hi * 4 + r;
                    if (kvg > qg0) s0[rt][r] = -INFINITY;
                    if (kvg > qg1) s1[rt][r] = -INFINITY;
                }
        }

        // ---- online softmax per group (exp2 domain, row = lx) ----
        #pragma unroll
        for (int g = 0; g < 2; ++g) {
            f32x4* s = g ? s1 : s0;
            float& m = g ? m1 : m0;
            float& l = g ? l1 : l0;
            f32x4* o = g ? o1 : o0;

            float tmax = s[0][0];
            #pragma unroll
            for (int rt = 0; rt < 4; ++rt)
                tmax = fmaxf(tmax, fmaxf(fmaxf(s[rt][0], s[rt][1]),
                                         fmaxf(s[rt][2], s[rt][3])));
            tmax = fmaxf(tmax, __shfl_xor(tmax, 16));
            tmax = fmaxf(tmax, __shfl_xor(tmax, 32));

            if (__any(tmax > m + DEFER_THR)) {
                float mn = fmaxf(m, tmax);
                float corr = fast_exp2(m - mn);
                m = mn;
                float ps = 0.f;
                #pragma unroll
                for (int rt = 0; rt < 4; ++rt)
                    #pragma unroll
                    for (int r = 0; r < 4; ++r) {
                        s[rt][r] = fast_exp2(s[rt][r] - mn);
                        ps += s[rt][r];
                    }
                ps += __shfl_xor(ps, 16);
                ps += __shfl_xor(ps, 32);
                l = l * corr + ps;
                #pragma unroll
                for (int r = 0; r < 4; ++r) {
                    float cr = __shfl(corr, hi * 4 + r);
                    #pragma unroll
                    for (int ct = 0; ct < 4; ++ct) o[ct][r] *= cr;
                }
            } else {                    // deferred: m unchanged, corr = 1
                float ps = 0.f;
                #pragma unroll
                for (int rt = 0; rt < 4; ++rt)
                    #pragma unroll
                    for (int r = 0; r < 4; ++r) {
                        s[rt][r] = fast_exp2(s[rt][r] - m);
                        ps += s[rt][r];
                    }
                ps += __shfl_xor(ps, 16);
                ps += __shfl_xor(ps, 32);
                l += ps;
            }

            // P -> bf16 -> per-(wave,group) swizzled LDS tile [16 q][64 kv]
            char* Pw = g ? Pw1 : Pw0;
            #pragma unroll
            for (int rt = 0; rt < 4; ++rt) {
                uint2 pk;
                pk.x = cvt_pk_bf16(s[rt][0], s[rt][1]);
                pk.y = cvt_pk_bf16(s[rt][2], s[rt][3]);
                int sl = 2 * rt + (hi >> 1);
                *(uint2*)&Pw[lx * 128 + ((sl ^ (lx & 7)) * 16) + (hi & 1) * 8] = pk;
            }
        }

        short8 pf0[2], pf1[2];
        #pragma unroll
        for (int ks = 0; ks < 2; ++ks) {
            int sl = ks * 4 + hi;
            pf0[ks] = *(const short8*)&Pw0[lx * 128 + ((sl ^ (lx & 7)) * 16)];
            pf1[ks] = *(const short8*)&Pw1[lx * 128 + ((sl ^ (lx & 7)) * 16)];
        }

        // ---- PV: each vf feeds both groups ----
        #pragma unroll
        for (int ct = 0; ct < 4; ++ct) {
            #pragma unroll
            for (int ks = 0; ks < 2; ++ks) {
                int row = ct * 16 + lx;
                int sp = (ks * 4 + hi) ^ (row & 7);
                short8 vf = *(const short8*)&bufc[8192 + row * 128 + sp * 16];
                o0[ct] = __builtin_amdgcn_mfma_f32_16x16x32_bf16(
                    pf0[ks], vf, o0[ct], 0, 0, 0);
                o1[ct] = __builtin_amdgcn_mfma_f32_16x16x32_bf16(
                    pf1[ks], vf, o1[ct], 0, 0, 0);
            }
        }

        SYNC_VM0();                     // t+1 landed; all waves done w/ bufc
        cur ^= 1;
    }

    // ---- epilogue: ctx bf16 [B,S,D] ----
    #pragma unroll
    for (int g = 0; g < 2; ++g) {
        f32x4* o = g ? o1 : o0;
        float lv = g ? l1 : l0;
        #pragma unroll
        for (int r = 0; r < 4; ++r) {
            float inv = 1.0f / __shfl(lv, hi * 4 + r);
            int srow = qt * 128 + wq * 32 + g * 16 + hi * 4 + r;
            #pragma unroll
            for (int ct = 0; ct < 4; ++ct)
                ctx[((size_t)(b * S_ + srow)) * D_ + h * 64 + ct * 16 + lx] =
                    f2bf(o[ct][r] * inv);
        }
    }
}

// ---------------------------------------------------------------------------
extern "C" void kernel_launch(void* const* d_in, const int* in_sizes, int n_in,
                              void* d_out, int out_size, void* d_ws, size_t ws_size,
                              hipStream_t stream)
{
    const float* x  = (const float*)d_in[0];
    const float* Wq = (const float*)d_in[1];
    const float* bq = (const float*)d_in[2];
    const float* Wk = (const float*)d_in[3];
    const float* bk = (const float*)d_in[4];
    const float* Wv = (const float*)d_in[5];
    const float* bv = (const float*)d_in[6];
    const float* Wo = (const float*)d_in[7];
    const float* bo = (const float*)d_in[8];
    float* out = (float*)d_out;

    const size_t per = (size_t)B_ * H_ * S_ * DH_;       // 4,194,304
    unsigned short* qb  = (unsigned short*)d_ws;
    unsigned short* kb  = qb + per;
    unsigned short* vtb = kb + per;
    unsigned short* xb  = vtb + per;
    unsigned short* wt  = xb + per;                      // 4 x 1M bf16
    unsigned short* cb  = xb;                            // ctx aliases xb

    cvt_x_k<<<2048, 256, 0, stream>>>(x, xb);
    tr_w_k<<<dim3(16, 16, 4), 256, 0, stream>>>(Wq, Wk, Wv, Wo, wt);

    gemm_bf16<1><<<dim3(32, 8, 3), 256, 0, stream>>>(
        xb, wt, bq, bk, bv, qb, kb, vtb);

    attn_mfma<<<dim3(32, 16), 256, 0, stream>>>(qb, kb, vtb, cb);

    gemm_bf16<0><<<dim3(32, 8, 1), 256, 0, stream>>>(
        cb, wt + 3u * 1048576u, bo, nullptr, nullptr, out, nullptr, nullptr);
}